// Round 7
// baseline (218.072 us; speedup 1.0000x reference)
//
#include <hip/hip_runtime.h>
#include <hip/hip_fp16.h>
#include <hip/hip_bf16.h>

#define M_REAL   54000
#define N_TOT    60000
#define N_EDGE   1000000

typedef __attribute__((ext_vector_type(8)))  short short8;
typedef __attribute__((ext_vector_type(16))) float f32x16;
typedef __attribute__((ext_vector_type(4)))  unsigned int uint4n;  // native vec for NT store

// ---------------------------------------------------------------------------
// Build: per edge, precompute everything, packed to 16 B per bucket slot:
//   .x = raw_row | remap_row<<16
//   .y = half2(u0,u1)  .z = half2(u2,v0)  .w = half2(v1,v2)
// Stores are NON-TEMPORAL: scattered 16B payloads, lines never reused before
// eviction -> bypass L2 allocation to cut write-back amplification.
// ---------------------------------------------------------------------------
__global__ void build_kernel(const int* __restrict__ row,
                             const int* __restrict__ col,
                             const int* __restrict__ ghost,
                             const float* __restrict__ positions,
                             const float* __restrict__ outpos,
                             const float* __restrict__ supportp,
                             int* __restrict__ counts,
                             uint4n* __restrict__ bucketData,
                             int maxdeg) {
    int e = blockIdx.x * blockDim.x + threadIdx.x;
    if (e >= N_EDGE) return;
    const int c = col[e];
    const int r = row[e];
    const int rm = (r < M_REAL) ? r : ghost[r];
    const float invs = 1.0f / supportp[0];
    float du = (outpos[2 * c]     - positions[2 * r])     * invs;
    float dv = (outpos[2 * c + 1] - positions[2 * r + 1]) * invs;
    du = fminf(fmaxf(du, -1.0f), 1.0f);
    dv = fminf(fmaxf(dv, -1.0f), 1.0f);
    const float u0 = __expf(-(du + 1.f) * (du + 1.f));
    const float u1 = __expf(-du * du);
    const float u2 = __expf(-(du - 1.f) * (du - 1.f));
    const float v0 = __expf(-(dv + 1.f) * (dv + 1.f));
    const float v1 = __expf(-dv * dv);
    const float v2 = __expf(-(dv - 1.f) * (dv - 1.f));
    __half2 h01 = __floats2half2_rn(u0, u1);
    __half2 h20 = __floats2half2_rn(u2, v0);
    __half2 h12 = __floats2half2_rn(v1, v2);
    uint4n d;
    d.x = (unsigned)r | ((unsigned)rm << 16);
    d.y = *reinterpret_cast<unsigned*>(&h01);
    d.z = *reinterpret_cast<unsigned*>(&h20);
    d.w = *reinterpret_cast<unsigned*>(&h12);
    int p = atomicAdd(&counts[c], 1);
    if (p < maxdeg)
        __builtin_nontemporal_store(d, &bucketData[(size_t)c * maxdeg + p]);
}

// Pad buckets to x4 with zero entries; store rounded count.
__global__ void pad_kernel(int* __restrict__ counts,
                           uint4n* __restrict__ bucketData,
                           int maxdeg) {
    int m = blockIdx.x * blockDim.x + threadIdx.x;
    if (m >= M_REAL) return;
    int deg = counts[m];
    if (deg > maxdeg) deg = maxdeg;
    int deg4 = (deg + 3) & ~3;
    uint4n z = {0u, 0u, 0u, 0u};
    for (int p = deg; p < deg4; ++p)
        bucketData[(size_t)m * maxdeg + p] = z;
    counts[m] = deg4;
}

// Convert W0,W1,W2 (f32 [288,32] each) to bf16 Wb[3][288*32].
__global__ void wprep_kernel(const float* __restrict__ W0,
                             const float* __restrict__ W1,
                             const float* __restrict__ W2,
                             unsigned short* __restrict__ Wb) {
    int i = blockIdx.x * blockDim.x + threadIdx.x;
    if (i >= 3 * 9216) return;
    const float* src = (i < 9216) ? W0 : (i < 2 * 9216 ? W1 : W2);
    __hip_bfloat16 b = __float2bfloat16(src[i % 9216]);
    Wb[i] = __builtin_bit_cast(unsigned short, b);
}

// Convert features f32 -> bf16 (gather source for layer 0), float4-vectorized.
__global__ void fcvt_kernel(const float* __restrict__ fin,
                            unsigned short* __restrict__ fout) {
    int i = blockIdx.x * blockDim.x + threadIdx.x;   // one float4 per thread
    if (i >= N_TOT * 32 / 4) return;
    float4 v = reinterpret_cast<const float4*>(fin)[i];
    ushort4 o;
    o.x = __builtin_bit_cast(unsigned short, __float2bfloat16(v.x));
    o.y = __builtin_bit_cast(unsigned short, __float2bfloat16(v.y));
    o.z = __builtin_bit_cast(unsigned short, __float2bfloat16(v.z));
    o.w = __builtin_bit_cast(unsigned short, __float2bfloat16(v.w));
    reinterpret_cast<ushort4*>(fout)[i] = o;
}

// ---------------------------------------------------------------------------
// Edge phase: one dst per half-wave, NO LDS, no block sync. Gathers bf16
// feature rows (64B/line per edge). Stores T[m,288] bf16, kk = b*32+lane.
// ---------------------------------------------------------------------------
__global__ __launch_bounds__(256) void edge_kernel(
        const unsigned short* __restrict__ xb,  // [*,32] bf16
        const int*   __restrict__ counts,       // [M] (x4-rounded)
        const uint4n* __restrict__ bucketData,  // [M*maxdeg]
        unsigned short* __restrict__ Tb,        // [M,288] bf16
        int use_hi, int maxdeg) {
    const int lane = threadIdx.x & 31;
    const int slot = threadIdx.x >> 5;
    const int m = blockIdx.x * 8 + slot;        // grid exact: M_REAL/8

    float t[9];
#pragma unroll
    for (int b = 0; b < 9; ++b) t[b] = 0.0f;

    const int deg4 = counts[m];
    const uint4n* bd = bucketData + (size_t)m * maxdeg;

    for (int i = 0; i < deg4; i += 4) {
        uint4n q[4];
#pragma unroll
        for (int j = 0; j < 4; ++j) q[j] = bd[i + j];
        float x[4];
#pragma unroll
        for (int j = 0; j < 4; ++j) {
            const unsigned rr = use_hi ? (q[j].x >> 16) : (q[j].x & 0xffffu);
            const unsigned us = xb[(size_t)rr * 32 + lane];
            x[j] = __builtin_bit_cast(float, us << 16);
        }
#pragma unroll
        for (int j = 0; j < 4; ++j) {
            unsigned qy = q[j].y, qz = q[j].z, qw = q[j].w;
            const float2 U01  = __half22float2(*reinterpret_cast<const __half2*>(&qy));
            const float2 U2V0 = __half22float2(*reinterpret_cast<const __half2*>(&qz));
            const float2 V12  = __half22float2(*reinterpret_cast<const __half2*>(&qw));
            const float xv = x[j];
            const float vx0 = U2V0.y * xv;
            const float vx1 = V12.x * xv;
            const float vx2 = V12.y * xv;
            t[0] += U01.x * vx0;  t[1] += U01.x * vx1;  t[2] += U01.x * vx2;
            t[3] += U01.y * vx0;  t[4] += U01.y * vx1;  t[5] += U01.y * vx2;
            t[6] += U2V0.x * vx0; t[7] += U2V0.x * vx1; t[8] += U2V0.x * vx2;
        }
    }

    unsigned short* tr = Tb + (size_t)m * 288 + lane;
#pragma unroll
    for (int b = 0; b < 9; ++b) {
        __hip_bfloat16 h = __float2bfloat16(t[b]);
        tr[b * 32] = __builtin_bit_cast(unsigned short, h);
    }
}

// ---------------------------------------------------------------------------
// GEMM: out[M,32] = T[M,288](bf16) x W[288,32](bf16), f32 accum.
// mfma_f32_32x32x16_bf16, 18 K-steps, 2 interleaved acc chains per wave.
// Writes bf16 (intermediate layers, gather source) or f32 (final layer).
// ---------------------------------------------------------------------------
__global__ __launch_bounds__(256) void gemm_kernel(
        const unsigned short* __restrict__ Tb,  // [M,288] bf16
        const unsigned short* __restrict__ Wb,  // [288,32] bf16
        float* __restrict__ youtf,              // [M,32] f32 (may be null)
        unsigned short* __restrict__ youtb,     // [M,32] bf16 (may be null)
        int act, int write_bf16) {
    const int wave = threadIdx.x >> 6;
    const int lane = threadIdx.x & 63;
    const int col  = lane & 31;
    const int kh   = lane >> 5;                 // 0/1
    const int m0   = blockIdx.x * 256 + wave * 64;

    short8 bfr[18];
#pragma unroll
    for (int s = 0; s < 18; ++s) {
        union { unsigned short u[8]; short8 v; } tmp;
#pragma unroll
        for (int j = 0; j < 8; ++j)
            tmp.u[j] = Wb[(s * 16 + kh * 8 + j) * 32 + col];
        bfr[s] = tmp.v;
    }

    const int r0 = m0 + (lane & 31);
    const int r1 = r0 + 32;
    const int r0c = (r0 < M_REAL) ? r0 : (M_REAL - 1);
    const int r1c = (r1 < M_REAL) ? r1 : (M_REAL - 1);
    const uint4n* a0 = reinterpret_cast<const uint4n*>(Tb + (size_t)r0c * 288) + kh;
    const uint4n* a1 = reinterpret_cast<const uint4n*>(Tb + (size_t)r1c * 288) + kh;

    f32x16 acc0 = {};
    f32x16 acc1 = {};
#pragma unroll
    for (int s = 0; s < 18; ++s) {
        union { uint4n u; short8 v; } av0, av1;
        av0.u = a0[s * 2];
        av1.u = a1[s * 2];
        acc0 = __builtin_amdgcn_mfma_f32_32x32x16_bf16(av0.v, bfr[s], acc0, 0, 0, 0);
        acc1 = __builtin_amdgcn_mfma_f32_32x32x16_bf16(av1.v, bfr[s], acc1, 0, 0, 0);
    }

#pragma unroll
    for (int r = 0; r < 16; ++r) {
        const int rr  = (r & 3) + 8 * (r >> 2) + 4 * kh;
        const int om0 = m0 + rr;
        const int om1 = m0 + 32 + rr;
        float v0 = acc0[r], v1 = acc1[r];
        if (act) { v0 = fmaxf(v0, 0.0f); v1 = fmaxf(v1, 0.0f); }
        if (write_bf16) {
            if (om0 < M_REAL)
                youtb[om0 * 32 + col] =
                    __builtin_bit_cast(unsigned short, __float2bfloat16(v0));
            if (om1 < M_REAL)
                youtb[om1 * 32 + col] =
                    __builtin_bit_cast(unsigned short, __float2bfloat16(v1));
        } else {
            if (om0 < M_REAL) youtf[om0 * 32 + col] = v0;
            if (om1 < M_REAL) youtf[om1 * 32 + col] = v1;
        }
    }
}

// Fill ghost rows of the final output: out[M+i] = out[ghost[M+i]]
__global__ void ghost_kernel(const int* __restrict__ ghost,
                             float* __restrict__ out) {
    int idx = blockIdx.x * blockDim.x + threadIdx.x;
    if (idx >= (N_TOT - M_REAL) * 32) return;
    int i = idx >> 5;
    int k = idx & 31;
    int g = ghost[M_REAL + i];
    out[(M_REAL + i) * 32 + k] = out[g * 32 + k];
}

extern "C" void kernel_launch(void* const* d_in, const int* in_sizes, int n_in,
                              void* d_out, int out_size, void* d_ws, size_t ws_size,
                              hipStream_t stream) {
    const float* positions = (const float*)d_in[0];
    const float* features  = (const float*)d_in[1];
    const float* outpos    = (const float*)d_in[2];
    const int*   ghost     = (const int*)d_in[3];
    const float* support   = (const float*)d_in[4];
    const int*   edge      = (const int*)d_in[5];   // [2,E]
    const float* W0        = (const float*)d_in[6];
    const float* W1        = (const float*)d_in[7];
    const float* W2        = (const float*)d_in[8];
    float* out = (float*)d_out;

    auto al = [](size_t x) { return (x + 255) & ~(size_t)255; };
    const size_t countsB = al((size_t)M_REAL * 4);
    const size_t TbB     = al((size_t)M_REAL * 288 * 2);
    const size_t WbB     = al((size_t)3 * 9216 * 2);
    const size_t xbB     = al((size_t)N_TOT * 32 * 2);
    const size_t obB     = al((size_t)M_REAL * 32 * 2);
    const size_t need64  = countsB + (size_t)M_REAL * 64 * 16 + TbB + WbB + xbB + 2 * obB;
    const int maxdeg = (ws_size >= need64) ? 64 : 48;

    char* ws = (char*)d_ws;
    int*            counts     = (int*)ws;            ws += countsB;
    uint4n*         bucketData = (uint4n*)ws;         ws += (size_t)M_REAL * maxdeg * 16;
    unsigned short* Tb         = (unsigned short*)ws; ws += TbB;
    unsigned short* Wb         = (unsigned short*)ws; ws += WbB;
    unsigned short* xb0        = (unsigned short*)ws; ws += xbB;
    unsigned short* ob0        = (unsigned short*)ws; ws += obB;
    unsigned short* ob1        = (unsigned short*)ws;

    const int* erow = edge;
    const int* ecol = edge + N_EDGE;

    (void)hipMemsetAsync(counts, 0, (size_t)M_REAL * 4, stream);
    build_kernel<<<(N_EDGE + 255) / 256, 256, 0, stream>>>(
        erow, ecol, ghost, positions, outpos, support, counts, bucketData, maxdeg);
    pad_kernel<<<(M_REAL + 255) / 256, 256, 0, stream>>>(counts, bucketData, maxdeg);
    wprep_kernel<<<(3 * 9216 + 255) / 256, 256, 0, stream>>>(W0, W1, W2, Wb);
    fcvt_kernel<<<(N_TOT * 32 / 4 + 255) / 256, 256, 0, stream>>>(features, xb0);

    const int egrid = M_REAL / 8;                 // 6750, exact
    const int ggrid = (M_REAL + 255) / 256;       // 211

    // layer 0: gather raw rows (lo16) from bf16 features
    edge_kernel<<<egrid, 256, 0, stream>>>(xb0, counts, bucketData, Tb, 0, maxdeg);
    gemm_kernel<<<ggrid, 256, 0, stream>>>(Tb, Wb, nullptr, ob0, 1, 1);
    // layer 1: gather remapped rows (hi16) from ob0
    edge_kernel<<<egrid, 256, 0, stream>>>(ob0, counts, bucketData, Tb, 1, maxdeg);
    gemm_kernel<<<ggrid, 256, 0, stream>>>(Tb, Wb + 9216, nullptr, ob1, 1, 1);
    // layer 2: no act, f32, write real rows of d_out
    edge_kernel<<<egrid, 256, 0, stream>>>(ob1, counts, bucketData, Tb, 1, maxdeg);
    gemm_kernel<<<ggrid, 256, 0, stream>>>(Tb, Wb + 2 * 9216, out, nullptr, 0, 0);

    ghost_kernel<<<((N_TOT - M_REAL) * 32 + 255) / 256, 256, 0, stream>>>(ghost, out);
}

// Round 8
// 215.092 us; speedup vs baseline: 1.0139x; 1.0139x over previous
//
#include <hip/hip_runtime.h>
#include <hip/hip_fp16.h>
#include <hip/hip_bf16.h>

#define M_REAL   54000
#define N_TOT    60000
#define N_EDGE   1000000

typedef __attribute__((ext_vector_type(8)))  short short8;
typedef __attribute__((ext_vector_type(16))) float f32x16;
typedef __attribute__((ext_vector_type(4)))  unsigned int uint4n;

// ---------------------------------------------------------------------------
// Build: per edge, precompute everything, packed to 16 B per bucket slot:
//   .x = raw_row | remap_row<<16
//   .y = half2(u0,u1)  .z = half2(u2,v0)  .w = half2(v1,v2)
// Plain stores (NT stores measured SLOWER: bypassing L2 write-combining).
// ---------------------------------------------------------------------------
__global__ void build_kernel(const int* __restrict__ row,
                             const int* __restrict__ col,
                             const int* __restrict__ ghost,
                             const float* __restrict__ positions,
                             const float* __restrict__ outpos,
                             const float* __restrict__ supportp,
                             int* __restrict__ counts,
                             uint4n* __restrict__ bucketData,
                             int maxdeg) {
    int e = blockIdx.x * blockDim.x + threadIdx.x;
    if (e >= N_EDGE) return;
    const int c = col[e];
    const int r = row[e];
    const int rm = (r < M_REAL) ? r : ghost[r];
    const float invs = 1.0f / supportp[0];
    float du = (outpos[2 * c]     - positions[2 * r])     * invs;
    float dv = (outpos[2 * c + 1] - positions[2 * r + 1]) * invs;
    du = fminf(fmaxf(du, -1.0f), 1.0f);
    dv = fminf(fmaxf(dv, -1.0f), 1.0f);
    const float u0 = __expf(-(du + 1.f) * (du + 1.f));
    const float u1 = __expf(-du * du);
    const float u2 = __expf(-(du - 1.f) * (du - 1.f));
    const float v0 = __expf(-(dv + 1.f) * (dv + 1.f));
    const float v1 = __expf(-dv * dv);
    const float v2 = __expf(-(dv - 1.f) * (dv - 1.f));
    __half2 h01 = __floats2half2_rn(u0, u1);
    __half2 h20 = __floats2half2_rn(u2, v0);
    __half2 h12 = __floats2half2_rn(v1, v2);
    uint4n d;
    d.x = (unsigned)r | ((unsigned)rm << 16);
    d.y = *reinterpret_cast<unsigned*>(&h01);
    d.z = *reinterpret_cast<unsigned*>(&h20);
    d.w = *reinterpret_cast<unsigned*>(&h12);
    int p = atomicAdd(&counts[c], 1);
    if (p < maxdeg) bucketData[(size_t)c * maxdeg + p] = d;
}

// Pad buckets to x8 with zero entries (zero u,v => zero contribution);
// store rounded count. x8 enables the edge kernel's 8-deep gather pipeline.
__global__ void pad_kernel(int* __restrict__ counts,
                           uint4n* __restrict__ bucketData,
                           int maxdeg) {
    int m = blockIdx.x * blockDim.x + threadIdx.x;
    if (m >= M_REAL) return;
    int deg = counts[m];
    if (deg > maxdeg) deg = maxdeg;
    int deg8 = (deg + 7) & ~7;
    uint4n z = {0u, 0u, 0u, 0u};
    for (int p = deg; p < deg8; ++p)
        bucketData[(size_t)m * maxdeg + p] = z;
    counts[m] = deg8;
}

// Convert W0,W1,W2 (f32 [288,32] each) to bf16 Wb[3][288*32].
__global__ void wprep_kernel(const float* __restrict__ W0,
                             const float* __restrict__ W1,
                             const float* __restrict__ W2,
                             unsigned short* __restrict__ Wb) {
    int i = blockIdx.x * blockDim.x + threadIdx.x;
    if (i >= 3 * 9216) return;
    const float* src = (i < 9216) ? W0 : (i < 2 * 9216 ? W1 : W2);
    __hip_bfloat16 b = __float2bfloat16(src[i % 9216]);
    Wb[i] = __builtin_bit_cast(unsigned short, b);
}

// Convert features f32 -> bf16 (gather source for layer 0), float4-vectorized.
__global__ void fcvt_kernel(const float* __restrict__ fin,
                            unsigned short* __restrict__ fout) {
    int i = blockIdx.x * blockDim.x + threadIdx.x;   // one float4 per thread
    if (i >= N_TOT * 32 / 4) return;
    float4 v = reinterpret_cast<const float4*>(fin)[i];
    ushort4 o;
    o.x = __builtin_bit_cast(unsigned short, __float2bfloat16(v.x));
    o.y = __builtin_bit_cast(unsigned short, __float2bfloat16(v.y));
    o.z = __builtin_bit_cast(unsigned short, __float2bfloat16(v.z));
    o.w = __builtin_bit_cast(unsigned short, __float2bfloat16(v.w));
    reinterpret_cast<ushort4*>(fout)[i] = o;
}

// ---------------------------------------------------------------------------
// Edge phase: one dst per half-wave, NO LDS, no block sync. 8 edges per
// iteration: 8 independent bucket loads then 8 independent feature-row
// gathers in flight (MLP-deep). Stores T[m,288] bf16, kk = b*32+lane.
// ---------------------------------------------------------------------------
__global__ __launch_bounds__(256) void edge_kernel(
        const unsigned short* __restrict__ xb,  // [*,32] bf16
        const int*   __restrict__ counts,       // [M] (x8-rounded)
        const uint4n* __restrict__ bucketData,  // [M*maxdeg]
        unsigned short* __restrict__ Tb,        // [M,288] bf16
        int use_hi, int maxdeg) {
    const int lane = threadIdx.x & 31;
    const int slot = threadIdx.x >> 5;
    const int m = blockIdx.x * 8 + slot;        // grid exact: M_REAL/8

    float t[9];
#pragma unroll
    for (int b = 0; b < 9; ++b) t[b] = 0.0f;

    const int deg8 = counts[m];
    const uint4n* bd = bucketData + (size_t)m * maxdeg;

    for (int i = 0; i < deg8; i += 8) {
        uint4n q[8];
#pragma unroll
        for (int j = 0; j < 8; ++j) q[j] = bd[i + j];
        float x[8];
#pragma unroll
        for (int j = 0; j < 8; ++j) {
            const unsigned rr = use_hi ? (q[j].x >> 16) : (q[j].x & 0xffffu);
            const unsigned us = xb[(size_t)rr * 32 + lane];
            x[j] = __builtin_bit_cast(float, us << 16);
        }
#pragma unroll
        for (int j = 0; j < 8; ++j) {
            unsigned qy = q[j].y, qz = q[j].z, qw = q[j].w;
            const float2 U01  = __half22float2(*reinterpret_cast<const __half2*>(&qy));
            const float2 U2V0 = __half22float2(*reinterpret_cast<const __half2*>(&qz));
            const float2 V12  = __half22float2(*reinterpret_cast<const __half2*>(&qw));
            const float xv = x[j];
            const float vx0 = U2V0.y * xv;
            const float vx1 = V12.x * xv;
            const float vx2 = V12.y * xv;
            t[0] += U01.x * vx0;  t[1] += U01.x * vx1;  t[2] += U01.x * vx2;
            t[3] += U01.y * vx0;  t[4] += U01.y * vx1;  t[5] += U01.y * vx2;
            t[6] += U2V0.x * vx0; t[7] += U2V0.x * vx1; t[8] += U2V0.x * vx2;
        }
    }

    unsigned short* tr = Tb + (size_t)m * 288 + lane;
#pragma unroll
    for (int b = 0; b < 9; ++b) {
        __hip_bfloat16 h = __float2bfloat16(t[b]);
        tr[b * 32] = __builtin_bit_cast(unsigned short, h);
    }
}

// ---------------------------------------------------------------------------
// GEMM: out[M,32] = T[M,288](bf16) x W[288,32](bf16), f32 accum.
// mfma_f32_32x32x16_bf16, 18 K-steps, 2 interleaved acc chains per wave.
// Writes bf16 (intermediate layers, gather source) or f32 (final layer).
// ---------------------------------------------------------------------------
__global__ __launch_bounds__(256) void gemm_kernel(
        const unsigned short* __restrict__ Tb,  // [M,288] bf16
        const unsigned short* __restrict__ Wb,  // [288,32] bf16
        float* __restrict__ youtf,              // [M,32] f32 (may be null)
        unsigned short* __restrict__ youtb,     // [M,32] bf16 (may be null)
        int act, int write_bf16) {
    const int wave = threadIdx.x >> 6;
    const int lane = threadIdx.x & 63;
    const int col  = lane & 31;
    const int kh   = lane >> 5;                 // 0/1
    const int m0   = blockIdx.x * 256 + wave * 64;

    short8 bfr[18];
#pragma unroll
    for (int s = 0; s < 18; ++s) {
        union { unsigned short u[8]; short8 v; } tmp;
#pragma unroll
        for (int j = 0; j < 8; ++j)
            tmp.u[j] = Wb[(s * 16 + kh * 8 + j) * 32 + col];
        bfr[s] = tmp.v;
    }

    const int r0 = m0 + (lane & 31);
    const int r1 = r0 + 32;
    const int r0c = (r0 < M_REAL) ? r0 : (M_REAL - 1);
    const int r1c = (r1 < M_REAL) ? r1 : (M_REAL - 1);
    const uint4n* a0 = reinterpret_cast<const uint4n*>(Tb + (size_t)r0c * 288) + kh;
    const uint4n* a1 = reinterpret_cast<const uint4n*>(Tb + (size_t)r1c * 288) + kh;

    f32x16 acc0 = {};
    f32x16 acc1 = {};
#pragma unroll
    for (int s = 0; s < 18; ++s) {
        union { uint4n u; short8 v; } av0, av1;
        av0.u = a0[s * 2];
        av1.u = a1[s * 2];
        acc0 = __builtin_amdgcn_mfma_f32_32x32x16_bf16(av0.v, bfr[s], acc0, 0, 0, 0);
        acc1 = __builtin_amdgcn_mfma_f32_32x32x16_bf16(av1.v, bfr[s], acc1, 0, 0, 0);
    }

#pragma unroll
    for (int r = 0; r < 16; ++r) {
        const int rr  = (r & 3) + 8 * (r >> 2) + 4 * kh;
        const int om0 = m0 + rr;
        const int om1 = m0 + 32 + rr;
        float v0 = acc0[r], v1 = acc1[r];
        if (act) { v0 = fmaxf(v0, 0.0f); v1 = fmaxf(v1, 0.0f); }
        if (write_bf16) {
            if (om0 < M_REAL)
                youtb[om0 * 32 + col] =
                    __builtin_bit_cast(unsigned short, __float2bfloat16(v0));
            if (om1 < M_REAL)
                youtb[om1 * 32 + col] =
                    __builtin_bit_cast(unsigned short, __float2bfloat16(v1));
        } else {
            if (om0 < M_REAL) youtf[om0 * 32 + col] = v0;
            if (om1 < M_REAL) youtf[om1 * 32 + col] = v1;
        }
    }
}

// Fill ghost rows of the final output: out[M+i] = out[ghost[M+i]]
__global__ void ghost_kernel(const int* __restrict__ ghost,
                             float* __restrict__ out) {
    int idx = blockIdx.x * blockDim.x + threadIdx.x;
    if (idx >= (N_TOT - M_REAL) * 32) return;
    int i = idx >> 5;
    int k = idx & 31;
    int g = ghost[M_REAL + i];
    out[(M_REAL + i) * 32 + k] = out[g * 32 + k];
}

extern "C" void kernel_launch(void* const* d_in, const int* in_sizes, int n_in,
                              void* d_out, int out_size, void* d_ws, size_t ws_size,
                              hipStream_t stream) {
    const float* positions = (const float*)d_in[0];
    const float* features  = (const float*)d_in[1];
    const float* outpos    = (const float*)d_in[2];
    const int*   ghost     = (const int*)d_in[3];
    const float* support   = (const float*)d_in[4];
    const int*   edge      = (const int*)d_in[5];   // [2,E]
    const float* W0        = (const float*)d_in[6];
    const float* W1        = (const float*)d_in[7];
    const float* W2        = (const float*)d_in[8];
    float* out = (float*)d_out;

    auto al = [](size_t x) { return (x + 255) & ~(size_t)255; };
    const size_t countsB = al((size_t)M_REAL * 4);
    const size_t TbB     = al((size_t)M_REAL * 288 * 2);
    const size_t WbB     = al((size_t)3 * 9216 * 2);
    const size_t xbB     = al((size_t)N_TOT * 32 * 2);
    const size_t obB     = al((size_t)M_REAL * 32 * 2);
    const size_t need64  = countsB + (size_t)M_REAL * 64 * 16 + TbB + WbB + xbB + 2 * obB;
    const int maxdeg = (ws_size >= need64) ? 64 : 48;

    char* ws = (char*)d_ws;
    int*            counts     = (int*)ws;            ws += countsB;
    uint4n*         bucketData = (uint4n*)ws;         ws += (size_t)M_REAL * maxdeg * 16;
    unsigned short* Tb         = (unsigned short*)ws; ws += TbB;
    unsigned short* Wb         = (unsigned short*)ws; ws += WbB;
    unsigned short* xb0        = (unsigned short*)ws; ws += xbB;
    unsigned short* ob0        = (unsigned short*)ws; ws += obB;
    unsigned short* ob1        = (unsigned short*)ws;

    const int* erow = edge;
    const int* ecol = edge + N_EDGE;

    (void)hipMemsetAsync(counts, 0, (size_t)M_REAL * 4, stream);
    build_kernel<<<(N_EDGE + 255) / 256, 256, 0, stream>>>(
        erow, ecol, ghost, positions, outpos, support, counts, bucketData, maxdeg);
    pad_kernel<<<(M_REAL + 255) / 256, 256, 0, stream>>>(counts, bucketData, maxdeg);
    wprep_kernel<<<(3 * 9216 + 255) / 256, 256, 0, stream>>>(W0, W1, W2, Wb);
    fcvt_kernel<<<(N_TOT * 32 / 4 + 255) / 256, 256, 0, stream>>>(features, xb0);

    const int egrid = M_REAL / 8;                 // 6750, exact
    const int ggrid = (M_REAL + 255) / 256;       // 211

    // layer 0: gather raw rows (lo16) from bf16 features
    edge_kernel<<<egrid, 256, 0, stream>>>(xb0, counts, bucketData, Tb, 0, maxdeg);
    gemm_kernel<<<ggrid, 256, 0, stream>>>(Tb, Wb, nullptr, ob0, 1, 1);
    // layer 1: gather remapped rows (hi16) from ob0
    edge_kernel<<<egrid, 256, 0, stream>>>(ob0, counts, bucketData, Tb, 1, maxdeg);
    gemm_kernel<<<ggrid, 256, 0, stream>>>(Tb, Wb + 9216, nullptr, ob1, 1, 1);
    // layer 2: no act, f32, write real rows of d_out
    edge_kernel<<<egrid, 256, 0, stream>>>(ob1, counts, bucketData, Tb, 1, maxdeg);
    gemm_kernel<<<ggrid, 256, 0, stream>>>(Tb, Wb + 2 * 9216, out, nullptr, 0, 0);

    ghost_kernel<<<((N_TOT - M_REAL) * 32 + 255) / 256, 256, 0, stream>>>(ghost, out);
}

// Round 9
// 194.490 us; speedup vs baseline: 1.1212x; 1.1059x over previous
//
#include <hip/hip_runtime.h>
#include <hip/hip_fp16.h>
#include <hip/hip_bf16.h>

#define M_REAL   54000
#define N_TOT    60000
#define N_EDGE   1000000

typedef __attribute__((ext_vector_type(8)))  short short8;
typedef __attribute__((ext_vector_type(16))) float f32x16;
typedef __attribute__((ext_vector_type(4)))  unsigned int uint4n;

// ---------------------------------------------------------------------------
// Build: per edge, precompute everything, packed to 16 B per bucket slot:
//   .x = raw_row | remap_row<<16
//   .y = half2(u0,u1)  .z = half2(u2,v0)  .w = half2(v1,v2)
// Plain stores (NT stores measured SLOWER; write amplification is structural).
// ---------------------------------------------------------------------------
__global__ void build_kernel(const int* __restrict__ row,
                             const int* __restrict__ col,
                             const int* __restrict__ ghost,
                             const float* __restrict__ positions,
                             const float* __restrict__ outpos,
                             const float* __restrict__ supportp,
                             int* __restrict__ counts,
                             uint4n* __restrict__ bucketData,
                             int maxdeg) {
    int e = blockIdx.x * blockDim.x + threadIdx.x;
    if (e >= N_EDGE) return;
    const int c = col[e];
    const int r = row[e];
    const int rm = (r < M_REAL) ? r : ghost[r];
    const float invs = 1.0f / supportp[0];
    float du = (outpos[2 * c]     - positions[2 * r])     * invs;
    float dv = (outpos[2 * c + 1] - positions[2 * r + 1]) * invs;
    du = fminf(fmaxf(du, -1.0f), 1.0f);
    dv = fminf(fmaxf(dv, -1.0f), 1.0f);
    const float u0 = __expf(-(du + 1.f) * (du + 1.f));
    const float u1 = __expf(-du * du);
    const float u2 = __expf(-(du - 1.f) * (du - 1.f));
    const float v0 = __expf(-(dv + 1.f) * (dv + 1.f));
    const float v1 = __expf(-dv * dv);
    const float v2 = __expf(-(dv - 1.f) * (dv - 1.f));
    __half2 h01 = __floats2half2_rn(u0, u1);
    __half2 h20 = __floats2half2_rn(u2, v0);
    __half2 h12 = __floats2half2_rn(v1, v2);
    uint4n d;
    d.x = (unsigned)r | ((unsigned)rm << 16);
    d.y = *reinterpret_cast<unsigned*>(&h01);
    d.z = *reinterpret_cast<unsigned*>(&h20);
    d.w = *reinterpret_cast<unsigned*>(&h12);
    int p = atomicAdd(&counts[c], 1);
    if (p < maxdeg) bucketData[(size_t)c * maxdeg + p] = d;
}

// Pad buckets to x4 with zero entries; store rounded count.
__global__ void pad_kernel(int* __restrict__ counts,
                           uint4n* __restrict__ bucketData,
                           int maxdeg) {
    int m = blockIdx.x * blockDim.x + threadIdx.x;
    if (m >= M_REAL) return;
    int deg = counts[m];
    if (deg > maxdeg) deg = maxdeg;
    int deg4 = (deg + 3) & ~3;
    uint4n z = {0u, 0u, 0u, 0u};
    for (int p = deg; p < deg4; ++p)
        bucketData[(size_t)m * maxdeg + p] = z;
    counts[m] = deg4;
}

// Convert W0,W1,W2 (f32 [288,32], layout [b*32+k][l]) to TRANSPOSED bf16
// Wt[3][32][288]: Wt[layer][l][k] = W[layer][k][l]. Each gemm lane then
// loads its 8-k B-fragment as ONE b128 instead of 8 scalar ushorts.
__global__ void wprep_kernel(const float* __restrict__ W0,
                             const float* __restrict__ W1,
                             const float* __restrict__ W2,
                             unsigned short* __restrict__ Wt) {
    int i = blockIdx.x * blockDim.x + threadIdx.x;   // [3][288][32] source idx
    if (i >= 3 * 9216) return;
    const int layer = i / 9216;
    const int rem   = i % 9216;
    const int k     = rem >> 5;          // 0..287
    const int l     = rem & 31;          // 0..31
    const float* src = (layer == 0) ? W0 : (layer == 1 ? W1 : W2);
    __hip_bfloat16 b = __float2bfloat16(src[rem]);
    Wt[layer * 9216 + l * 288 + k] = __builtin_bit_cast(unsigned short, b);
}

// ---------------------------------------------------------------------------
// Edge phase (r5-proven config): one dst per half-wave, no LDS, no block
// sync, f32 feature gathers, 4 edges/iteration. Stores T[m,288] bf16 with
// kk = b*32+lane.
// ---------------------------------------------------------------------------
__global__ __launch_bounds__(256) void edge_kernel(
        const float* __restrict__ xin,        // [*,32] f32
        const int*   __restrict__ counts,     // [M] (x4-rounded)
        const uint4n* __restrict__ bucketData,// [M*maxdeg]
        unsigned short* __restrict__ Tb,      // [M,288] bf16
        int use_hi, int maxdeg) {
    const int lane = threadIdx.x & 31;
    const int slot = threadIdx.x >> 5;
    const int m = blockIdx.x * 8 + slot;      // grid exact: M_REAL/8

    float t[9];
#pragma unroll
    for (int b = 0; b < 9; ++b) t[b] = 0.0f;

    const int deg4 = counts[m];
    const uint4n* bd = bucketData + (size_t)m * maxdeg;

    for (int i = 0; i < deg4; i += 4) {
        uint4n q[4];
#pragma unroll
        for (int j = 0; j < 4; ++j) q[j] = bd[i + j];
        float x[4];
#pragma unroll
        for (int j = 0; j < 4; ++j) {
            const unsigned rr = use_hi ? (q[j].x >> 16) : (q[j].x & 0xffffu);
            x[j] = xin[(size_t)rr * 32 + lane];
        }
#pragma unroll
        for (int j = 0; j < 4; ++j) {
            unsigned qy = q[j].y, qz = q[j].z, qw = q[j].w;
            const float2 U01  = __half22float2(*reinterpret_cast<const __half2*>(&qy));
            const float2 U2V0 = __half22float2(*reinterpret_cast<const __half2*>(&qz));
            const float2 V12  = __half22float2(*reinterpret_cast<const __half2*>(&qw));
            const float xv = x[j];
            const float vx0 = U2V0.y * xv;
            const float vx1 = V12.x * xv;
            const float vx2 = V12.y * xv;
            t[0] += U01.x * vx0;  t[1] += U01.x * vx1;  t[2] += U01.x * vx2;
            t[3] += U01.y * vx0;  t[4] += U01.y * vx1;  t[5] += U01.y * vx2;
            t[6] += U2V0.x * vx0; t[7] += U2V0.x * vx1; t[8] += U2V0.x * vx2;
        }
    }

    unsigned short* tr = Tb + (size_t)m * 288 + lane;
#pragma unroll
    for (int b = 0; b < 9; ++b) {
        __hip_bfloat16 h = __float2bfloat16(t[b]);
        tr[b * 32] = __builtin_bit_cast(unsigned short, h);
    }
}

// ---------------------------------------------------------------------------
// GEMM: out[M,32] = T[M,288](bf16) x W[288,32](bf16), f32 accum, opt relu.
// One 32-row tile per wave: grid 422 x 4 waves = 1688 tiles (1.65 waves/SIMD,
// 2x the old TLP). Per wave: 18 A b128 + 18 B b128 (all independent) then an
// 18-MFMA chain. B comes from transposed Wt so the 8-k fragment is contiguous.
// A frag: row = lane&31, k = (lane>>5)*8 + j. B frag: col = lane&31, same k.
// C/D: col = lane&31, row = (reg&3) + 8*(reg>>2) + 4*(lane>>5).
// ---------------------------------------------------------------------------
__global__ __launch_bounds__(256, 2) void gemm_kernel(
        const unsigned short* __restrict__ Tb,  // [M,288] bf16
        const unsigned short* __restrict__ Wt,  // [32,288] bf16 (transposed)
        float* __restrict__ yout,               // [M,32] f32
        int act) {
    const int wave = threadIdx.x >> 6;
    const int lane = threadIdx.x & 63;
    const int col  = lane & 31;
    const int kh   = lane >> 5;                 // 0/1
    const int m0   = (blockIdx.x * 4 + wave) * 32;

    const int row  = m0 + col;
    const int rowc = (row < M_REAL) ? row : (M_REAL - 1);
    const uint4n* a = reinterpret_cast<const uint4n*>(Tb + (size_t)rowc * 288) + kh;
    const uint4n* b = reinterpret_cast<const uint4n*>(Wt + (size_t)col * 288) + kh;

    f32x16 acc = {};
#pragma unroll
    for (int s = 0; s < 18; ++s) {
        union { uint4n u; short8 v; } av, bv;
        av.u = a[s * 2];
        bv.u = b[s * 2];
        acc = __builtin_amdgcn_mfma_f32_32x32x16_bf16(av.v, bv.v, acc, 0, 0, 0);
    }

#pragma unroll
    for (int r = 0; r < 16; ++r) {
        const int rr = (r & 3) + 8 * (r >> 2) + 4 * kh;
        const int om = m0 + rr;
        float v = acc[r];
        if (act) v = fmaxf(v, 0.0f);
        if (om < M_REAL) yout[om * 32 + col] = v;
    }
}

// Fill ghost rows of the final output: out[M+i] = out[ghost[M+i]]
__global__ void ghost_kernel(const int* __restrict__ ghost,
                             float* __restrict__ out) {
    int idx = blockIdx.x * blockDim.x + threadIdx.x;
    if (idx >= (N_TOT - M_REAL) * 32) return;
    int i = idx >> 5;
    int k = idx & 31;
    int g = ghost[M_REAL + i];
    out[(M_REAL + i) * 32 + k] = out[g * 32 + k];
}

extern "C" void kernel_launch(void* const* d_in, const int* in_sizes, int n_in,
                              void* d_out, int out_size, void* d_ws, size_t ws_size,
                              hipStream_t stream) {
    const float* positions = (const float*)d_in[0];
    const float* features  = (const float*)d_in[1];
    const float* outpos    = (const float*)d_in[2];
    const int*   ghost     = (const int*)d_in[3];
    const float* support   = (const float*)d_in[4];
    const int*   edge      = (const int*)d_in[5];   // [2,E]
    const float* W0        = (const float*)d_in[6];
    const float* W1        = (const float*)d_in[7];
    const float* W2        = (const float*)d_in[8];
    float* out = (float*)d_out;

    auto al = [](size_t x) { return (x + 255) & ~(size_t)255; };
    const size_t countsB = al((size_t)M_REAL * 4);
    const size_t TbB     = al((size_t)M_REAL * 288 * 2);
    const size_t WtB     = al((size_t)3 * 9216 * 2);
    const size_t outB    = al((size_t)M_REAL * 32 * 4);
    const size_t need64  = countsB + (size_t)M_REAL * 64 * 16 + TbB + WtB + outB;
    const int maxdeg = (ws_size >= need64) ? 64 : 48;

    char* ws = (char*)d_ws;
    int*            counts     = (int*)ws;            ws += countsB;
    uint4n*         bucketData = (uint4n*)ws;         ws += (size_t)M_REAL * maxdeg * 16;
    unsigned short* Tb         = (unsigned short*)ws; ws += TbB;
    unsigned short* Wt         = (unsigned short*)ws; ws += WtB;
    float*          out1       = (float*)ws;
    float*          out0       = out;   // reuse d_out real-row region as scratch

    const int* erow = edge;
    const int* ecol = edge + N_EDGE;

    (void)hipMemsetAsync(counts, 0, (size_t)M_REAL * 4, stream);
    build_kernel<<<(N_EDGE + 255) / 256, 256, 0, stream>>>(
        erow, ecol, ghost, positions, outpos, support, counts, bucketData, maxdeg);
    pad_kernel<<<(M_REAL + 255) / 256, 256, 0, stream>>>(counts, bucketData, maxdeg);
    wprep_kernel<<<(3 * 9216 + 255) / 256, 256, 0, stream>>>(W0, W1, W2, Wt);

    const int egrid = M_REAL / 8;                 // 6750, exact
    const int ggrid = 422;                        // 422*4 waves = 1688 tiles

    // layer 0: gather raw rows (lo16) from f32 features
    edge_kernel<<<egrid, 256, 0, stream>>>(features, counts, bucketData, Tb, 0, maxdeg);
    gemm_kernel<<<ggrid, 256, 0, stream>>>(Tb, Wt, out0, 1);
    // layer 1: gather remapped rows (hi16) from out0
    edge_kernel<<<egrid, 256, 0, stream>>>(out0, counts, bucketData, Tb, 1, maxdeg);
    gemm_kernel<<<ggrid, 256, 0, stream>>>(Tb, Wt + 9216, out1, 1);
    // layer 2: no act, write real rows of d_out
    edge_kernel<<<egrid, 256, 0, stream>>>(out1, counts, bucketData, Tb, 1, maxdeg);
    gemm_kernel<<<ggrid, 256, 0, stream>>>(Tb, Wt + 2 * 9216, out, 0);

    ghost_kernel<<<((N_TOT - M_REAL) * 32 + 255) / 256, 256, 0, stream>>>(ghost, out);
}